// Round 1
// baseline (122.150 us; speedup 1.0000x reference)
//
#include <hip/hip_runtime.h>

// 4-layer MLP: [B,64] -> 4 -> 8 -> 8 -> 32, sigmoid after each layer.
// All f32. Memory-bound: 256 MB read + 128 MB write -> ~61 us floor @ 6.3 TB/s.

#define IN_DIM 64
#define OUT_DIM 32

__device__ __forceinline__ float fast_sigmoid(float z) {
    // 1/(1+exp(-z)); __expf -> v_exp_f32 path, rcp approx (~1 ulp) — far
    // inside the 1.28e-2 absmax threshold.
    float e = __expf(-z);
    return __builtin_amdgcn_rcpf(1.0f + e);
}

__global__ __launch_bounds__(256) void mlp4_kernel(
    const float* __restrict__ x,
    const float* __restrict__ W0, const float* __restrict__ b0,
    const float* __restrict__ W1, const float* __restrict__ b1,
    const float* __restrict__ W2, const float* __restrict__ b2,
    const float* __restrict__ W3, const float* __restrict__ b3,
    float* __restrict__ out, int batch)
{
    // Stage all weights/biases in LDS once per block (~2.6 KB).
    __shared__ float sW0[4 * 64];   // W0[c][k] = sW0[c*64+k]
    __shared__ float sb0[4];
    __shared__ float sW1[8 * 4];    // W1[j][c]
    __shared__ float sb1[8];
    __shared__ float sW2[8 * 8];    // W2[j][i]
    __shared__ float sb2[8];
    __shared__ float sW3[32 * 8];   // W3[o][j]
    __shared__ float sb3[32];

    const int tid = threadIdx.x;
    if (tid < 256) { sW0[tid] = W0[tid]; sW3[tid] = W3[tid]; }
    if (tid < 64)  { sW2[tid] = W2[tid]; }
    if (tid < 32)  { sW1[tid] = W1[tid]; sb3[tid] = b3[tid]; }
    if (tid < 8)   { sb1[tid] = b1[tid]; sb2[tid] = b2[tid]; }
    if (tid < 4)   { sb0[tid] = b0[tid]; }
    __syncthreads();

    const int row = blockIdx.x * 256 + tid;
    if (row >= batch) return;

    // ---- Load this row's 64 inputs as 16x float4 (coalesced 16 B/lane) ----
    float xr[IN_DIM];
    const float4* xp = reinterpret_cast<const float4*>(x + (size_t)row * IN_DIM);
    #pragma unroll
    for (int j = 0; j < IN_DIM / 4; ++j) {
        float4 v = xp[j];
        xr[4 * j + 0] = v.x;
        xr[4 * j + 1] = v.y;
        xr[4 * j + 2] = v.z;
        xr[4 * j + 3] = v.w;
    }

    // ---- Layer 0: 64 -> 4 ----
    float h0[4];
    #pragma unroll
    for (int c = 0; c < 4; ++c) {
        float acc = sb0[c];
        #pragma unroll
        for (int k = 0; k < IN_DIM; ++k)
            acc = fmaf(xr[k], sW0[c * IN_DIM + k], acc);  // contiguous LDS -> ds_read_b128
        h0[c] = fast_sigmoid(acc);
    }

    // ---- Layer 1: 4 -> 8 ----
    float h1[8];
    #pragma unroll
    for (int j = 0; j < 8; ++j) {
        float acc = sb1[j];
        #pragma unroll
        for (int c = 0; c < 4; ++c)
            acc = fmaf(h0[c], sW1[j * 4 + c], acc);
        h1[j] = fast_sigmoid(acc);
    }

    // ---- Layer 2: 8 -> 8 ----
    float h2[8];
    #pragma unroll
    for (int j = 0; j < 8; ++j) {
        float acc = sb2[j];
        #pragma unroll
        for (int i = 0; i < 8; ++i)
            acc = fmaf(h1[i], sW2[j * 8 + i], acc);
        h2[j] = fast_sigmoid(acc);
    }

    // ---- Layer 3: 8 -> 32, compute 4 outputs at a time and store float4 ----
    float4* op = reinterpret_cast<float4*>(out + (size_t)row * OUT_DIM);
    #pragma unroll
    for (int q = 0; q < OUT_DIM / 4; ++q) {
        float o[4];
        #pragma unroll
        for (int r = 0; r < 4; ++r) {
            const int oidx = q * 4 + r;
            float acc = sb3[oidx];
            #pragma unroll
            for (int j = 0; j < 8; ++j)
                acc = fmaf(h2[j], sW3[oidx * 8 + j], acc);
            o[r] = fast_sigmoid(acc);
        }
        op[q] = make_float4(o[0], o[1], o[2], o[3]);
    }
}

extern "C" void kernel_launch(void* const* d_in, const int* in_sizes, int n_in,
                              void* d_out, int out_size, void* d_ws, size_t ws_size,
                              hipStream_t stream) {
    const float* x  = (const float*)d_in[0];
    const float* W0 = (const float*)d_in[1];
    const float* b0 = (const float*)d_in[2];
    const float* W1 = (const float*)d_in[3];
    const float* b1 = (const float*)d_in[4];
    const float* W2 = (const float*)d_in[5];
    const float* b2 = (const float*)d_in[6];
    const float* W3 = (const float*)d_in[7];
    const float* b3 = (const float*)d_in[8];
    float* out = (float*)d_out;

    const int batch = in_sizes[0] / IN_DIM;  // 1,000,000
    const int threads = 256;
    const int blocks = (batch + threads - 1) / threads;

    mlp4_kernel<<<blocks, threads, 0, stream>>>(x, W0, b0, W1, b1, W2, b2, W3, b3,
                                                out, batch);
}